// Round 1
// baseline (435.785 us; speedup 1.0000x reference)
//
#include <hip/hip_runtime.h>
#include <stdint.h>

// ASH percentile-threshold: per-row (B=512) 90th-percentile (np linear interp)
// then keep strictly-greater values, else 0.
// One block per row; 3-pass radix select (11/11/10 bits) on sortable uint keys
// with LDS histograms, tracking both order stats k0 and k0+1; pass 4 thresholds.

constexpr int ROW_LEN      = 2048 * 49;          // 100352 elements per row
constexpr int THREADS      = 512;
constexpr int VEC4_PER_ROW = ROW_LEN / 4;        // 25088
constexpr int ITERS        = VEC4_PER_ROW / THREADS; // 49 exactly

__device__ __forceinline__ uint32_t f2s(float f) {
    uint32_t u = __float_as_uint(f);
    return (u & 0x80000000u) ? ~u : (u | 0x80000000u);
}
__device__ __forceinline__ float s2f(uint32_t u) {
    uint32_t b = (u & 0x80000000u) ? (u ^ 0x80000000u) : ~u;
    return __uint_as_float(b);
}

// Block-wide: find bucket b such that prefix[b] <= target < prefix[b]+hist[b].
// Writes sout[0]=bucket, sout[1]=count strictly below bucket. All threads call.
template <int NB>
__device__ void select_bucket(const uint32_t* __restrict__ hist, uint32_t target,
                              uint32_t* sscan, uint32_t* sout) {
    const int tid = threadIdx.x;
    constexpr int CH = NB / THREADS;   // 4 or 2
    uint32_t s = 0;
#pragma unroll
    for (int j = 0; j < CH; ++j) s += hist[tid * CH + j];
    sscan[tid] = s;
    __syncthreads();
    // Hillis-Steele inclusive scan over 512 per-thread sums
    for (int off = 1; off < THREADS; off <<= 1) {
        uint32_t v = (tid >= off) ? sscan[tid - off] : 0u;
        __syncthreads();
        sscan[tid] += v;
        __syncthreads();
    }
    uint32_t run = sscan[tid] - s;   // exclusive prefix of this thread's chunk
#pragma unroll
    for (int j = 0; j < CH; ++j) {
        uint32_t c = hist[tid * CH + j];
        if (c != 0u && target >= run && target < run + c) {
            sout[0] = (uint32_t)(tid * CH + j);   // unique writer
            sout[1] = run;
        }
        run += c;
    }
    __syncthreads();
}

__global__ __launch_bounds__(THREADS)
void ash_kernel(const float* __restrict__ x, const int* __restrict__ kp,
                float* __restrict__ out) {
    __shared__ uint32_t h0[2048];
    __shared__ uint32_t h1[2048];
    __shared__ uint32_t sscan[THREADS];
    __shared__ uint32_t sout[4];     // bucket0, below0, bucket1, below1
    __shared__ float sth;

    const int tid = threadIdx.x;
    const size_t rowoff = (size_t)blockIdx.x * (size_t)ROW_LEN;
    const float4* __restrict__ xr = reinterpret_cast<const float4*>(x + rowoff);

    // ---- order-statistic indices (np.percentile linear interpolation)
    const int kpv = *kp;
    double q = (double)kpv / 100.0;
    double vidx = q * (double)(ROW_LEN - 1);
    if (vidx < 0.0) vidx = 0.0;
    if (vidx > (double)(ROW_LEN - 1)) vidx = (double)(ROW_LEN - 1);
    uint32_t k0 = (uint32_t)vidx;                       // floor (vidx >= 0)
    double frac = vidx - (double)k0;
    uint32_t k1 = (k0 + 1u < (uint32_t)ROW_LEN) ? k0 + 1u : k0;

    uint32_t pref0 = 0, pref1 = 0, base0 = 0, base1 = 0;

    // =========== PASS 1: bits 31..21 (2048 buckets) ===========
    for (int i = tid; i < 2048; i += THREADS) h0[i] = 0u;
    __syncthreads();
    for (int it = 0; it < ITERS; ++it) {
        float4 f = xr[it * THREADS + tid];
        atomicAdd(&h0[f2s(f.x) >> 21], 1u);
        atomicAdd(&h0[f2s(f.y) >> 21], 1u);
        atomicAdd(&h0[f2s(f.z) >> 21], 1u);
        atomicAdd(&h0[f2s(f.w) >> 21], 1u);
    }
    __syncthreads();
    select_bucket<2048>(h0, k0, sscan, sout);
    select_bucket<2048>(h0, k1, sscan, sout + 2);
    pref0 = sout[0] << 21; base0 = sout[1];
    pref1 = sout[2] << 21; base1 = sout[3];
    __syncthreads();

    // =========== PASS 2: bits 20..10 (2048 buckets) ===========
    for (int i = tid; i < 2048; i += THREADS) { h0[i] = 0u; h1[i] = 0u; }
    __syncthreads();
    {
        const bool same = (pref0 == pref1);
        const uint32_t p0 = pref0 >> 21, p1 = pref1 >> 21;
        for (int it = 0; it < ITERS; ++it) {
            float4 f = xr[it * THREADS + tid];
            uint32_t u;
            u = f2s(f.x);
            if ((u >> 21) == p0) atomicAdd(&h0[(u >> 10) & 0x7FFu], 1u);
            if (!same && (u >> 21) == p1) atomicAdd(&h1[(u >> 10) & 0x7FFu], 1u);
            u = f2s(f.y);
            if ((u >> 21) == p0) atomicAdd(&h0[(u >> 10) & 0x7FFu], 1u);
            if (!same && (u >> 21) == p1) atomicAdd(&h1[(u >> 10) & 0x7FFu], 1u);
            u = f2s(f.z);
            if ((u >> 21) == p0) atomicAdd(&h0[(u >> 10) & 0x7FFu], 1u);
            if (!same && (u >> 21) == p1) atomicAdd(&h1[(u >> 10) & 0x7FFu], 1u);
            u = f2s(f.w);
            if ((u >> 21) == p0) atomicAdd(&h0[(u >> 10) & 0x7FFu], 1u);
            if (!same && (u >> 21) == p1) atomicAdd(&h1[(u >> 10) & 0x7FFu], 1u);
        }
        __syncthreads();
        select_bucket<2048>(h0, k0 - base0, sscan, sout);
        select_bucket<2048>(same ? h0 : h1, k1 - base1, sscan, sout + 2);
        pref0 |= sout[0] << 10; base0 += sout[1];
        pref1 |= sout[2] << 10; base1 += sout[3];
        __syncthreads();
    }

    // =========== PASS 3: bits 9..0 (1024 buckets) ===========
    for (int i = tid; i < 2048; i += THREADS) { h0[i] = 0u; h1[i] = 0u; }
    __syncthreads();
    {
        const bool same = (pref0 == pref1);
        const uint32_t p0 = pref0 >> 10, p1 = pref1 >> 10;
        for (int it = 0; it < ITERS; ++it) {
            float4 f = xr[it * THREADS + tid];
            uint32_t u;
            u = f2s(f.x);
            if ((u >> 10) == p0) atomicAdd(&h0[u & 0x3FFu], 1u);
            if (!same && (u >> 10) == p1) atomicAdd(&h1[u & 0x3FFu], 1u);
            u = f2s(f.y);
            if ((u >> 10) == p0) atomicAdd(&h0[u & 0x3FFu], 1u);
            if (!same && (u >> 10) == p1) atomicAdd(&h1[u & 0x3FFu], 1u);
            u = f2s(f.z);
            if ((u >> 10) == p0) atomicAdd(&h0[u & 0x3FFu], 1u);
            if (!same && (u >> 10) == p1) atomicAdd(&h1[u & 0x3FFu], 1u);
            u = f2s(f.w);
            if ((u >> 10) == p0) atomicAdd(&h0[u & 0x3FFu], 1u);
            if (!same && (u >> 10) == p1) atomicAdd(&h1[u & 0x3FFu], 1u);
        }
        __syncthreads();
        select_bucket<1024>(h0, k0 - base0, sscan, sout);
        select_bucket<1024>(same ? h0 : h1, k1 - base1, sscan, sout + 2);
        if (tid == 0) {
            uint32_t key0 = pref0 | sout[0];
            uint32_t key1 = pref1 | sout[2];
            double v0 = (double)s2f(key0);
            double v1 = (double)s2f(key1);
            double t = frac;
            double th;
            if (t >= 0.5) th = v1 - (v1 - v0) * (1.0 - t);   // numpy _lerp form
            else          th = v0 + (v1 - v0) * t;
            sth = (float)th;
        }
        __syncthreads();
    }

    // =========== PASS 4: threshold & write ===========
    const float th = sth;
    float4* __restrict__ orow = reinterpret_cast<float4*>(out + rowoff);
    for (int it = 0; it < ITERS; ++it) {
        float4 f = xr[it * THREADS + tid];
        f.x = (f.x > th) ? f.x : 0.0f;
        f.y = (f.y > th) ? f.y : 0.0f;
        f.z = (f.z > th) ? f.z : 0.0f;
        f.w = (f.w > th) ? f.w : 0.0f;
        orow[it * THREADS + tid] = f;
    }
}

extern "C" void kernel_launch(void* const* d_in, const int* in_sizes, int n_in,
                              void* d_out, int out_size, void* d_ws, size_t ws_size,
                              hipStream_t stream) {
    const float* x  = (const float*)d_in[0];
    const int*   kp = (const int*)d_in[1];
    float*       out = (float*)d_out;
    const int rows = in_sizes[0] / ROW_LEN;   // 512
    hipLaunchKernelGGL(ash_kernel, dim3(rows), dim3(THREADS), 0, stream,
                       x, kp, out);
}

// Round 2
// 391.220 us; speedup vs baseline: 1.1139x; 1.1139x over previous
//
#include <hip/hip_runtime.h>
#include <stdint.h>

// ASH percentile-threshold, round 2.
// One 1024-thread block per row (B=512). 3 global passes:
//   P1: read + 4x-replicated 2048-bucket LDS histogram (key top 11 bits)
//   P2: read + compact candidates (elements in k0/k1's top bucket) to LDS,
//       finish remaining 21 radix bits entirely in LDS (global fallback if overflow)
//   P3: read + threshold + write (nontemporal).

typedef float v4f __attribute__((ext_vector_type(4)));

constexpr int ROW_LEN = 2048 * 49;            // 100352
constexpr int THREADS = 1024;
constexpr int VEC4    = ROW_LEN / 4;          // 25088
constexpr int FULL    = VEC4 / THREADS;       // 24
constexpr int TAIL    = VEC4 - FULL * THREADS; // 512
constexpr int CAP     = 8192;

__device__ __forceinline__ uint32_t f2s(float f) {
    uint32_t u = __float_as_uint(f);
    return (u & 0x80000000u) ? ~u : (u | 0x80000000u);
}
__device__ __forceinline__ float s2f(uint32_t u) {
    uint32_t b = (u & 0x80000000u) ? (u ^ 0x80000000u) : ~u;
    return __uint_as_float(b);
}
__device__ __forceinline__ uint32_t umax_(uint32_t a, uint32_t b) { return a > b ? a : b; }
__device__ __forceinline__ uint32_t umin_(uint32_t a, uint32_t b) { return a < b ? a : b; }

// Block-wide: find bucket b with prefix[b] <= target < prefix[b]+hist[b].
// sout[0]=bucket, sout[1]=count strictly below bucket. Ends with __syncthreads.
template <int NB>
__device__ void select_bucket(const uint32_t* __restrict__ hist, uint32_t target,
                              uint32_t* sscan, uint32_t* sout) {
    const int tid = threadIdx.x;
    constexpr int CH = NB / THREADS;   // 2 or 1
    uint32_t s = 0;
#pragma unroll
    for (int j = 0; j < CH; ++j) s += hist[tid * CH + j];
    sscan[tid] = s;
    __syncthreads();
    for (int off = 1; off < THREADS; off <<= 1) {
        uint32_t v = (tid >= off) ? sscan[tid - off] : 0u;
        __syncthreads();
        sscan[tid] += v;
        __syncthreads();
    }
    uint32_t run = sscan[tid] - s;
#pragma unroll
    for (int j = 0; j < CH; ++j) {
        uint32_t c = hist[tid * CH + j];
        if (c != 0u && target >= run && target < run + c) {
            sout[0] = (uint32_t)(tid * CH + j);
            sout[1] = run;
        }
        run += c;
    }
    __syncthreads();
}

__global__ __launch_bounds__(THREADS, 8)
void ash_kernel(const float* __restrict__ x, const int* __restrict__ kp,
                float* __restrict__ out) {
    __shared__ uint32_t hist[4][2048];   // P1 replicated; later hist[0]/hist[1] reused
    __shared__ uint32_t cand[CAP];
    __shared__ uint32_t sscan[THREADS];
    __shared__ uint32_t sout[4];
    __shared__ uint32_t scnt;

    const int tid = threadIdx.x;
    const size_t rowoff = (size_t)blockIdx.x * (size_t)ROW_LEN;
    const v4f* __restrict__ xr = reinterpret_cast<const v4f*>(x + rowoff);

    // ---- order-statistic indices (np.percentile linear interpolation)
    const int kpv = *kp;
    double q = (double)kpv / 100.0;
    double vidx = q * (double)(ROW_LEN - 1);
    if (vidx < 0.0) vidx = 0.0;
    if (vidx > (double)(ROW_LEN - 1)) vidx = (double)(ROW_LEN - 1);
    uint32_t k0 = (uint32_t)vidx;
    double frac = vidx - (double)k0;
    uint32_t k1 = (k0 + 1u < (uint32_t)ROW_LEN) ? k0 + 1u : k0;

    // =========== PASS 1: replicated histogram over key>>21 ===========
    {
        uint32_t* hflat = &hist[0][0];
        for (int i = tid; i < 4 * 2048; i += THREADS) hflat[i] = 0u;
    }
    __syncthreads();
    {
        uint32_t* hrep = hist[(tid >> 6) & 3];
#pragma unroll 2
        for (int it = 0; it < FULL / 2; ++it) {
            v4f a = xr[(2 * it) * THREADS + tid];
            v4f b = xr[(2 * it + 1) * THREADS + tid];
            atomicAdd(&hrep[f2s(a.x) >> 21], 1u);
            atomicAdd(&hrep[f2s(a.y) >> 21], 1u);
            atomicAdd(&hrep[f2s(a.z) >> 21], 1u);
            atomicAdd(&hrep[f2s(a.w) >> 21], 1u);
            atomicAdd(&hrep[f2s(b.x) >> 21], 1u);
            atomicAdd(&hrep[f2s(b.y) >> 21], 1u);
            atomicAdd(&hrep[f2s(b.z) >> 21], 1u);
            atomicAdd(&hrep[f2s(b.w) >> 21], 1u);
        }
        if (tid < TAIL) {
            v4f a = xr[FULL * THREADS + tid];
            atomicAdd(&hrep[f2s(a.x) >> 21], 1u);
            atomicAdd(&hrep[f2s(a.y) >> 21], 1u);
            atomicAdd(&hrep[f2s(a.z) >> 21], 1u);
            atomicAdd(&hrep[f2s(a.w) >> 21], 1u);
        }
    }
    __syncthreads();
    for (int i = tid; i < 2048; i += THREADS)
        hist[0][i] += hist[1][i] + hist[2][i] + hist[3][i];
    __syncthreads();
    select_bucket<2048>(hist[0], k0, sscan, sout);
    select_bucket<2048>(hist[0], k1, sscan, sout + 2);
    const uint32_t p0 = sout[0], base0 = sout[1];
    const uint32_t p1 = sout[2], base1 = sout[3];
    __syncthreads();

    // =========== PASS 2: compact candidates to LDS ===========
    if (tid == 0) scnt = 0u;
    __syncthreads();
    {
        auto push = [&](uint32_t u) {
            uint32_t pr = u >> 21;
            if (pr == p0 || pr == p1) {
                uint32_t idx = atomicAdd(&scnt, 1u);
                if (idx < (uint32_t)CAP) cand[idx] = u;
            }
        };
#pragma unroll 2
        for (int it = 0; it < FULL / 2; ++it) {
            v4f a = xr[(2 * it) * THREADS + tid];
            v4f b = xr[(2 * it + 1) * THREADS + tid];
            push(f2s(a.x)); push(f2s(a.y)); push(f2s(a.z)); push(f2s(a.w));
            push(f2s(b.x)); push(f2s(b.y)); push(f2s(b.z)); push(f2s(b.w));
        }
        if (tid < TAIL) {
            v4f a = xr[FULL * THREADS + tid];
            push(f2s(a.x)); push(f2s(a.y)); push(f2s(a.z)); push(f2s(a.w));
        }
    }
    __syncthreads();
    const uint32_t cnt = scnt;

    uint32_t key0, key1;
    if (cnt <= (uint32_t)CAP) {
        // ---------- in-LDS finish ----------
        if (p0 == p1) {
            // level 2: bits 20..10
            for (int i = tid; i < 2048; i += THREADS) hist[0][i] = 0u;
            __syncthreads();
            for (int i = tid; i < (int)cnt; i += THREADS)
                atomicAdd(&hist[0][(cand[i] >> 10) & 0x7FFu], 1u);
            __syncthreads();
            select_bucket<2048>(hist[0], k0 - base0, sscan, sout);
            select_bucket<2048>(hist[0], k1 - base0, sscan, sout + 2);
            const uint32_t m0 = sout[0], b0 = sout[1];
            const uint32_t m1 = sout[2], b1 = sout[3];
            __syncthreads();
            // level 3: bits 9..0
            for (int i = tid; i < 2048; i += THREADS) { hist[0][i] = 0u; hist[1][i] = 0u; }
            __syncthreads();
            for (int i = tid; i < (int)cnt; i += THREADS) {
                uint32_t u = cand[i];
                uint32_t m = (u >> 10) & 0x7FFu;
                if (m == m0) atomicAdd(&hist[0][u & 0x3FFu], 1u);
                if (m1 != m0 && m == m1) atomicAdd(&hist[1][u & 0x3FFu], 1u);
            }
            __syncthreads();
            select_bucket<1024>(hist[0], (k0 - base0) - b0, sscan, sout);
            select_bucket<1024>((m1 == m0) ? hist[0] : hist[1], (k1 - base0) - b1,
                                sscan, sout + 2);
            key0 = (p0 << 21) | (m0 << 10) | sout[0];
            key1 = (p0 << 21) | (m1 << 10) | sout[2];
        } else {
            // k0 is the max of bucket p0; k1 is the min of bucket p1.
            uint32_t lmax = 0u, lmin = 0xFFFFFFFFu;
            for (int i = tid; i < (int)cnt; i += THREADS) {
                uint32_t u = cand[i];
                if ((u >> 21) == p0) lmax = umax_(lmax, u);
                else                 lmin = umin_(lmin, u);
            }
            sscan[tid] = lmax;
            __syncthreads();
            for (int off = THREADS / 2; off > 0; off >>= 1) {
                if (tid < off) sscan[tid] = umax_(sscan[tid], sscan[tid + off]);
                __syncthreads();
            }
            key0 = sscan[0];
            __syncthreads();
            sscan[tid] = lmin;
            __syncthreads();
            for (int off = THREADS / 2; off > 0; off >>= 1) {
                if (tid < off) sscan[tid] = umin_(sscan[tid], sscan[tid + off]);
                __syncthreads();
            }
            key1 = sscan[0];
            __syncthreads();
        }
    } else {
        // ---------- overflow fallback: global-read radix passes ----------
        uint32_t bb0 = base0, bb1 = base1;
        for (int i = tid; i < 2048; i += THREADS) { hist[0][i] = 0u; hist[1][i] = 0u; }
        __syncthreads();
        const bool same = (p0 == p1);
        for (int i = tid; i < VEC4; i += THREADS) {
            v4f a = xr[i];
            uint32_t u;
            u = f2s(a.x);
            if ((u >> 21) == p0) atomicAdd(&hist[0][(u >> 10) & 0x7FFu], 1u);
            if (!same && (u >> 21) == p1) atomicAdd(&hist[1][(u >> 10) & 0x7FFu], 1u);
            u = f2s(a.y);
            if ((u >> 21) == p0) atomicAdd(&hist[0][(u >> 10) & 0x7FFu], 1u);
            if (!same && (u >> 21) == p1) atomicAdd(&hist[1][(u >> 10) & 0x7FFu], 1u);
            u = f2s(a.z);
            if ((u >> 21) == p0) atomicAdd(&hist[0][(u >> 10) & 0x7FFu], 1u);
            if (!same && (u >> 21) == p1) atomicAdd(&hist[1][(u >> 10) & 0x7FFu], 1u);
            u = f2s(a.w);
            if ((u >> 21) == p0) atomicAdd(&hist[0][(u >> 10) & 0x7FFu], 1u);
            if (!same && (u >> 21) == p1) atomicAdd(&hist[1][(u >> 10) & 0x7FFu], 1u);
        }
        __syncthreads();
        select_bucket<2048>(hist[0], k0 - bb0, sscan, sout);
        select_bucket<2048>(same ? hist[0] : hist[1], k1 - bb1, sscan, sout + 2);
        const uint32_t q0 = (p0 << 11) | sout[0]; bb0 += sout[1];
        const uint32_t q1 = (p1 << 11) | sout[2]; bb1 += sout[3];
        __syncthreads();
        for (int i = tid; i < 2048; i += THREADS) { hist[0][i] = 0u; hist[1][i] = 0u; }
        __syncthreads();
        const bool same2 = (q0 == q1);
        for (int i = tid; i < VEC4; i += THREADS) {
            v4f a = xr[i];
            uint32_t u;
            u = f2s(a.x);
            if ((u >> 10) == q0) atomicAdd(&hist[0][u & 0x3FFu], 1u);
            if (!same2 && (u >> 10) == q1) atomicAdd(&hist[1][u & 0x3FFu], 1u);
            u = f2s(a.y);
            if ((u >> 10) == q0) atomicAdd(&hist[0][u & 0x3FFu], 1u);
            if (!same2 && (u >> 10) == q1) atomicAdd(&hist[1][u & 0x3FFu], 1u);
            u = f2s(a.z);
            if ((u >> 10) == q0) atomicAdd(&hist[0][u & 0x3FFu], 1u);
            if (!same2 && (u >> 10) == q1) atomicAdd(&hist[1][u & 0x3FFu], 1u);
            u = f2s(a.w);
            if ((u >> 10) == q0) atomicAdd(&hist[0][u & 0x3FFu], 1u);
            if (!same2 && (u >> 10) == q1) atomicAdd(&hist[1][u & 0x3FFu], 1u);
        }
        __syncthreads();
        select_bucket<1024>(hist[0], k0 - bb0, sscan, sout);
        select_bucket<1024>(same2 ? hist[0] : hist[1], k1 - bb1, sscan, sout + 2);
        key0 = (q0 << 10) | sout[0];
        key1 = (q1 << 10) | sout[2];
    }

    // ---- threshold (all threads; numpy _lerp in f64, cast to f32)
    double v0 = (double)s2f(key0);
    double v1 = (double)s2f(key1);
    double th_d = (frac >= 0.5) ? v1 - (v1 - v0) * (1.0 - frac)
                                : v0 + (v1 - v0) * frac;
    const float th = (float)th_d;

    // =========== PASS 3: threshold & write (nontemporal) ===========
    v4f* __restrict__ orow = reinterpret_cast<v4f*>(out + rowoff);
#pragma unroll 2
    for (int it = 0; it < FULL / 2; ++it) {
        v4f a = __builtin_nontemporal_load(&xr[(2 * it) * THREADS + tid]);
        v4f b = __builtin_nontemporal_load(&xr[(2 * it + 1) * THREADS + tid]);
        a.x = (a.x > th) ? a.x : 0.0f;
        a.y = (a.y > th) ? a.y : 0.0f;
        a.z = (a.z > th) ? a.z : 0.0f;
        a.w = (a.w > th) ? a.w : 0.0f;
        b.x = (b.x > th) ? b.x : 0.0f;
        b.y = (b.y > th) ? b.y : 0.0f;
        b.z = (b.z > th) ? b.z : 0.0f;
        b.w = (b.w > th) ? b.w : 0.0f;
        __builtin_nontemporal_store(a, &orow[(2 * it) * THREADS + tid]);
        __builtin_nontemporal_store(b, &orow[(2 * it + 1) * THREADS + tid]);
    }
    if (tid < TAIL) {
        v4f a = __builtin_nontemporal_load(&xr[FULL * THREADS + tid]);
        a.x = (a.x > th) ? a.x : 0.0f;
        a.y = (a.y > th) ? a.y : 0.0f;
        a.z = (a.z > th) ? a.z : 0.0f;
        a.w = (a.w > th) ? a.w : 0.0f;
        __builtin_nontemporal_store(a, &orow[FULL * THREADS + tid]);
    }
}

extern "C" void kernel_launch(void* const* d_in, const int* in_sizes, int n_in,
                              void* d_out, int out_size, void* d_ws, size_t ws_size,
                              hipStream_t stream) {
    const float* x  = (const float*)d_in[0];
    const int*   kp = (const int*)d_in[1];
    float*       out = (float*)d_out;
    const int rows = in_sizes[0] / ROW_LEN;   // 512
    hipLaunchKernelGGL(ash_kernel, dim3(rows), dim3(THREADS), 0, stream,
                       x, kp, out);
}